// Round 19
// baseline (1033.343 us; speedup 1.0000x reference)
//
#include <hip/hip_runtime.h>

typedef unsigned short u16;
typedef __bf16 bf16x8 __attribute__((ext_vector_type(8)));
typedef float f32x4 __attribute__((ext_vector_type(4)));

__device__ __forceinline__ u16 f2bf(float f) {
    unsigned u = __builtin_bit_cast(unsigned, f);
    u += 0x7fffu + ((u >> 16) & 1u);
    return (u16)(u >> 16);
}
__device__ __forceinline__ float bf2f(u16 v) {
    unsigned u = ((unsigned)v) << 16;
    return __builtin_bit_cast(float, u);
}
__device__ __forceinline__ void glds16(const void* g, void* l) {
    __builtin_amdgcn_global_load_lds(
        (const __attribute__((address_space(1))) unsigned*)g,
        (__attribute__((address_space(3))) unsigned*)l, 16, 0, 0);
}

// chunked XCD-local mapping
__device__ __forceinline__ void xcd_map(int bid, int nloc, int TM, int& tm, int& tn)
{
    const int xcd = bid & 7;
    int l = bid >> 3;
    const int per = nloc << 3;
    const int fullC = TM >> 3;
    const int lFull = fullC * per;
    int c, tn_l, tmIn;
    if (l < lFull) { c = l / per; int r = l - c * per; tn_l = r >> 3; tmIn = r & 7; }
    else { int r = l - lFull; int sc = TM - (fullC << 3); c = fullC; tn_l = r / sc; tmIn = r % sc; }
    tm = (c << 3) + tmIn;
    tn = xcd * nloc + tn_l;
}

// pair-swizzle helpers for BK=32 (64B data rows, 128B LDS pairs, 8 phys slots)
__device__ __forceinline__ void swz_src(int r, int sp, int& rs, int& ks)
{
    int e = (((r & 1) << 2) | sp) ^ ((r >> 1) & 7);
    rs = (r & ~1) | (e >> 2);
    ks = e & 3;
}
__device__ __forceinline__ int swz_rd(int row, int lg)
{
    int s8 = (((row & 1) << 2) | lg) ^ ((row >> 1) & 7);
    return (row >> 1) * 128 + s8 * 16;
}

// ---------------- stable partition of tokens by mask: perm = [text..., vision...]
__global__ __launch_bounds__(1024) void build_perm(
    const int* __restrict__ mask, int* __restrict__ perm, int* __restrict__ counts)
{
    __shared__ int sc[1024];
    int t = threadIdx.x;
    int m[4], cnt = 0;
#pragma unroll
    for (int j = 0; j < 4; j++) {
        m[j] = mask[t * 4 + j] != 0;
        cnt += (m[j] == 0);
    }
    sc[t] = cnt;
    __syncthreads();
    for (int off = 1; off < 1024; off <<= 1) {
        int v = (t >= off) ? sc[t - off] : 0;
        __syncthreads();
        sc[t] += v;
        __syncthreads();
    }
    int totT = sc[1023];
    int exT = sc[t] - cnt;
    int exV = t * 4 - exT;
    int pT = exT, pV = totT + exV;
#pragma unroll
    for (int j = 0; j < 4; j++) {
        if (m[j] == 0) perm[pT++] = t * 4 + j;
        else           perm[pV++] = t * 4 + j;
    }
    if (t == 0) { counts[0] = totT; counts[1] = 4096 - totT; }
}

// ---------------- weight transpose + f32->bf16:  W[K][N] f32 -> Wt[N][K] bf16
__global__ __launch_bounds__(256) void transpose_bf16(
    const float* __restrict__ W, u16* __restrict__ Wt, int Kd, int Nd)
{
    __shared__ float tile[64][65];
    int k0 = blockIdx.x * 64, n0 = blockIdx.y * 64;
    int t = threadIdx.x;
    int rr = t >> 4, cc = (t & 15) * 4;
#pragma unroll
    for (int i = 0; i < 4; i++) {
        float4 v = *(const float4*)&W[(long)(k0 + i * 16 + rr) * Nd + n0 + cc];
        tile[i * 16 + rr][cc]     = v.x;
        tile[i * 16 + rr][cc + 1] = v.y;
        tile[i * 16 + rr][cc + 2] = v.z;
        tile[i * 16 + rr][cc + 3] = v.w;
    }
    __syncthreads();
    int nn = t >> 3, k8 = (t & 7) * 8;
#pragma unroll
    for (int i = 0; i < 2; i++) {
        int n = i * 32 + nn;
        u16 pk[8];
#pragma unroll
        for (int j = 0; j < 8; j++) pk[j] = f2bf(tile[k8 + j][n]);
        *(uint4*)&Wt[(long)(n0 + n) * Kd + k0 + k8] = *(const uint4*)pk;
    }
}

// ---------------- rmsnorm (row of 2048, f32 in) -> bf16 out
__global__ __launch_bounds__(256) void rms_x(
    const float* __restrict__ x, const float* __restrict__ w, u16* __restrict__ out)
{
    long row = blockIdx.x;
    int t = threadIdx.x, wave = t >> 6, lane = t & 63;
    const float4* x4 = (const float4*)(x + row * 2048);
    float4 a = x4[2 * t], b = x4[2 * t + 1];
    float ss = a.x*a.x + a.y*a.y + a.z*a.z + a.w*a.w
             + b.x*b.x + b.y*b.y + b.z*b.z + b.w*b.w;
#pragma unroll
    for (int m = 1; m < 64; m <<= 1) ss += __shfl_xor(ss, m);
    __shared__ float red[4];
    if (lane == 0) red[wave] = ss;
    __syncthreads();
    float tot = red[0] + red[1] + red[2] + red[3];
    float inv = rsqrtf(tot * (1.0f / 2048.0f) + 1e-6f);
    const float4* w4 = (const float4*)w;
    float4 wa = w4[2 * t], wb = w4[2 * t + 1];
    u16* op = out + row * 2048 + t * 8;
    op[0] = f2bf(a.x * inv * wa.x); op[1] = f2bf(a.y * inv * wa.y);
    op[2] = f2bf(a.z * inv * wa.z); op[3] = f2bf(a.w * inv * wa.w);
    op[4] = f2bf(b.x * inv * wb.x); op[5] = f2bf(b.y * inv * wb.y);
    op[6] = f2bf(b.z * inv * wb.z); op[7] = f2bf(b.w * inv * wb.w);
}

// ---------------- grouped GEMM, 128x256 tile, BK=32, 8 waves (2Mx4N), wave 64x64.
// Ring-3 LDS = 72KB -> 2 blocks/CU. Counted vmcnt(3), 1 barrier per K-tile.
// Pair-swizzled LDS. EPI 1: C bf16.
template <int EPI, bool PG, bool PC>
__global__ __launch_bounds__(512, 4) void gemm32(
    const u16* __restrict__ A, const u16* __restrict__ Bt0, const u16* __restrict__ Bt1,
    void* __restrict__ Cv,
    const int* __restrict__ perm, const int* __restrict__ counts, int N, int K)
{
    extern __shared__ u16 lds[];   // 3 x (A 8KB + B 16KB) = 72KB
    int tm, tn;
    xcd_map(blockIdx.x, N >> 11, 33, tm, tn);
    const int nT = counts[0];
    const int tT = (nT + 127) >> 7, tV = (4096 - nT + 127) >> 7;
    if (tm >= tT + tV) return;
    const bool vis = tm >= tT;
    const u16* Bt = vis ? Bt1 : Bt0;
    const int rowbase = vis ? nT + (tm - tT) * 128 : tm * 128;
    const int rowlim = vis ? 4096 : nT;
    const int tid = threadIdx.x;
    const int wave = tid >> 6, lane = tid & 63;
    const int wrbase = (wave >> 2) * 64, wcbase = (wave & 3) * 64;
    const int lr = lane & 15, lg = lane >> 4;
    const int n0 = tn * 256;
    const int t4 = tid >> 2, sp = tid & 3;
    const char* aSrc;
    const char* bSrc[2];
    {
        int rs, ks; swz_src(t4, sp, rs, ks);
        int gr = rowbase + rs; gr = gr < 4095 ? gr : 4095;
        long ar = PG ? perm[gr] : gr;
        aSrc = (const char*)A + ar * (long)K * 2 + ks * 16;
    }
#pragma unroll
    for (int c = 0; c < 2; c++) {
        int r = c * 128 + t4;
        int rs, ks; swz_src(r, sp, rs, ks);
        bSrc[c] = (const char*)Bt + (long)(n0 + rs) * K * 2 + ks * 16;
    }
    auto stage = [&](int kt, int bu) {
        char* ab = (char*)lds + bu * 24576;
        long ko = (long)kt * 64;
        glds16(aSrc + ko, ab + tid * 16);
#pragma unroll
        for (int c = 0; c < 2; c++)
            glds16(bSrc[c] + ko, ab + 8192 + c * 8192 + tid * 16);
    };
    auto ldA = [&](int bu, int mi) -> bf16x8 {
        const char* ab = (const char*)lds + bu * 24576;
        int row = wrbase + mi * 16 + lr;
        return *(const bf16x8*)(ab + swz_rd(row, lg));
    };
    auto ldB = [&](int bu, int ni) -> bf16x8 {
        const char* bb = (const char*)lds + bu * 24576 + 8192;
        int row = wcbase + ni * 16 + lr;
        return *(const bf16x8*)(bb + swz_rd(row, lg));
    };

    f32x4 acc[4][4] = {};
    const int nkt = K >> 5;
    stage(0, 0);
    stage(1, 1);
    for (int kt = 0; kt < nkt; ++kt) {
        const int bu = kt % 3;
        if (kt == nkt - 1) asm volatile("s_waitcnt vmcnt(0)" ::: "memory");
        else               asm volatile("s_waitcnt vmcnt(3)" ::: "memory");
        __builtin_amdgcn_s_barrier();
        if (kt + 2 < nkt) stage(kt + 2, (kt + 2) % 3);
        bf16x8 af[4], bq[4];
#pragma unroll
        for (int i = 0; i < 4; i++) af[i] = ldA(bu, i);
#pragma unroll
        for (int j = 0; j < 4; j++) bq[j] = ldB(bu, j);
        __builtin_amdgcn_s_setprio(1);
#pragma unroll
        for (int i = 0; i < 4; i++)
#pragma unroll
            for (int j = 0; j < 4; j++)
                acc[i][j] = __builtin_amdgcn_mfma_f32_16x16x32_bf16(
                    af[i], bq[j], acc[i][j], 0, 0, 0);
        __builtin_amdgcn_s_setprio(0);
    }
#pragma unroll
    for (int mi = 0; mi < 4; mi++)
#pragma unroll
        for (int r = 0; r < 4; r++) {
            int gr = rowbase + wrbase + mi * 16 + lg * 4 + r;
            if (gr >= rowlim) continue;
            long crow = PC ? (long)perm[gr] : (long)gr;
#pragma unroll
            for (int ni = 0; ni < 4; ni++) {
                long col = n0 + wcbase + ni * 16 + lr;
                ((u16*)Cv)[crow * (long)N + col] = f2bf(acc[mi][ni][r]);
            }
        }
}

// ---------------- fused gate+up, 128M x dual-128N, BK=32.
// Drain double-buffer ring-2 = 48KB -> 3 blocks/CU (LDS-limited).
// launch_bounds(512,4): r14's (512,6) spilled accumulators (VGPR 60->40); (512,4)
// keeps VGPR cap 128 -> no spill. Pair-swizzled LDS. e1 = silu(A@Wg)*(A@Wu).
__global__ __launch_bounds__(512, 4) void gemm_gu(
    const u16* __restrict__ A,
    const u16* __restrict__ Bg0, const u16* __restrict__ Bg1,
    const u16* __restrict__ Bu0, const u16* __restrict__ Bu1,
    u16* __restrict__ C,
    const int* __restrict__ perm, const int* __restrict__ counts, int N, int K)
{
    extern __shared__ u16 lds[];   // 2 x (A 8KB + Bg 8KB + Bu 8KB) = 48KB
    int tm, tn;
    xcd_map(blockIdx.x, N >> 10, 33, tm, tn);
    const int nT = counts[0];
    const int tT = (nT + 127) >> 7, tV = (4096 - nT + 127) >> 7;
    if (tm >= tT + tV) return;
    const bool vis = tm >= tT;
    const u16* Bg = vis ? Bg1 : Bg0;
    const u16* Bu = vis ? Bu1 : Bu0;
    const int rowbase = vis ? nT + (tm - tT) * 128 : tm * 128;
    const int rowlim = vis ? 4096 : nT;
    const int tid = threadIdx.x;
    const int wave = tid >> 6, lane = tid & 63;
    const int wrbase = (wave >> 2) * 64, wcbase = (wave & 3) * 32;
    const int lr = lane & 15, lg = lane >> 4;
    const int n0 = tn * 128;
    const int t4 = tid >> 2, sp = tid & 3;
    const char *aSrc, *gSrc, *uSrc;
    {
        int rs, ks; swz_src(t4, sp, rs, ks);
        int gr = rowbase + rs; gr = gr < 4095 ? gr : 4095;
        long ar = (long)perm[gr];
        aSrc = (const char*)A + ar * (long)K * 2 + ks * 16;
        gSrc = (const char*)Bg + (long)(n0 + rs) * K * 2 + ks * 16;
        uSrc = (const char*)Bu + (long)(n0 + rs) * K * 2 + ks * 16;
    }
    auto stage = [&](int kt, int bu) {
        char* ab = (char*)lds + bu * 24576;
        long ko = (long)kt * 64;
        glds16(aSrc + ko, ab + tid * 16);
        glds16(gSrc + ko, ab + 8192 + tid * 16);
        glds16(uSrc + ko, ab + 16384 + tid * 16);
    };
    auto ldA = [&](int bu, int mi) -> bf16x8 {
        const char* ab = (const char*)lds + bu * 24576;
        int row = wrbase + mi * 16 + lr;
        return *(const bf16x8*)(ab + swz_rd(row, lg));
    };
    auto ldGU = [&](int bu, int sub, int ni) -> bf16x8 {
        const char* p = (const char*)lds + bu * 24576 + 8192 + sub * 8192;
        int row = wcbase + ni * 16 + lr;
        return *(const bf16x8*)(p + swz_rd(row, lg));
    };

    f32x4 accg[4][2] = {}, accu[4][2] = {};
    const int nkt = K >> 5;
    stage(0, 0);
    for (int kt = 0; kt < nkt; ++kt) {
        const int bu = kt & 1;
        __syncthreads();                 // stage(kt) landed; prior buf reads closed
        if (kt + 1 < nkt) stage(kt + 1, bu ^ 1);
        bf16x8 af[4], bg[2], bv[2];
#pragma unroll
        for (int i = 0; i < 4; i++) af[i] = ldA(bu, i);
#pragma unroll
        for (int j = 0; j < 2; j++) {
            bg[j] = ldGU(bu, 0, j);
            bv[j] = ldGU(bu, 1, j);
        }
        __builtin_amdgcn_s_setprio(1);
#pragma unroll
        for (int i = 0; i < 4; i++)
#pragma unroll
            for (int j = 0; j < 2; j++) {
                accg[i][j] = __builtin_amdgcn_mfma_f32_16x16x32_bf16(
                    af[i], bg[j], accg[i][j], 0, 0, 0);
                accu[i][j] = __builtin_amdgcn_mfma_f32_16x16x32_bf16(
                    af[i], bv[j], accu[i][j], 0, 0, 0);
            }
        __builtin_amdgcn_s_setprio(0);
    }
#pragma unroll
    for (int mi = 0; mi < 4; mi++)
#pragma unroll
        for (int r = 0; r < 4; r++) {
            int gr = rowbase + wrbase + mi * 16 + lg * 4 + r;
            if (gr >= rowlim) continue;
#pragma unroll
            for (int ni = 0; ni < 2; ni++) {
                long col = n0 + wcbase + ni * 16 + lr;
                float g = accg[mi][ni][r], u = accu[mi][ni][r];
                C[(long)gr * N + col] = f2bf(g / (1.0f + __expf(-g)) * u);
            }
        }
}

// ---------------- grouped GEMM, 128x128 tile, BK=32, drain double-buffer 32KB,
// pair-swizzled (r15-proven). Used for O-proj AND down-proj.
// EPI 2: C f32 = resid[idx] + acc.
template <int EPI, bool PG, bool PC>
__global__ __launch_bounds__(512, 4) void gemmsq(
    const u16* __restrict__ A, const u16* __restrict__ Bt0, const u16* __restrict__ Bt1,
    void* __restrict__ Cv, const float* __restrict__ resid,
    const int* __restrict__ perm, const int* __restrict__ counts, int N, int K)
{
    extern __shared__ u16 lds[];   // 2 x (A 8KB + B 8KB) = 32KB
    int tm, tn;
    xcd_map(blockIdx.x, N >> 10, 33, tm, tn);
    const int nT = counts[0];
    const int tT = (nT + 127) >> 7, tV = (4096 - nT + 127) >> 7;
    if (tm >= tT + tV) return;
    const bool vis = tm >= tT;
    const u16* Bt = vis ? Bt1 : Bt0;
    const int rowbase = vis ? nT + (tm - tT) * 128 : tm * 128;
    const int rowlim = vis ? 4096 : nT;
    const int tid = threadIdx.x;
    const int wave = tid >> 6, lane = tid & 63;
    const int wrbase = (wave >> 2) * 64, wcbase = (wave & 3) * 32;
    const int lr = lane & 15, lg = lane >> 4;
    const int n0 = tn * 128;
    const int t4 = tid >> 2, sp = tid & 3;
    const char *aSrc, *bSrc;
    {
        int rs, ks; swz_src(t4, sp, rs, ks);
        int gr = rowbase + rs; gr = gr < 4095 ? gr : 4095;
        long ar = PG ? (long)perm[gr] : (long)gr;
        aSrc = (const char*)A + ar * (long)K * 2 + ks * 16;
        bSrc = (const char*)Bt + (long)(n0 + rs) * K * 2 + ks * 16;
    }
    auto stage = [&](int kt, int bu) {
        char* ab = (char*)lds + bu * 16384;
        long ko = (long)kt * 64;
        glds16(aSrc + ko, ab + tid * 16);
        glds16(bSrc + ko, ab + 8192 + tid * 16);
    };
    auto ldA = [&](int bu, int mi) -> bf16x8 {
        const char* ab = (const char*)lds + bu * 16384;
        int row = wrbase + mi * 16 + lr;
        return *(const bf16x8*)(ab + swz_rd(row, lg));
    };
    auto ldB = [&](int bu, int ni) -> bf16x8 {
        const char* bb = (const char*)lds + bu * 16384 + 8192;
        int row = wcbase + ni * 16 + lr;
        return *(const bf16x8*)(bb + swz_rd(row, lg));
    };

    f32x4 acc[4][2] = {};
    const int nkt = K >> 5;
    stage(0, 0);
    for (int kt = 0; kt < nkt; ++kt) {
        const int bu = kt & 1;
        __syncthreads();
        if (kt + 1 < nkt) stage(kt + 1, bu ^ 1);
        bf16x8 af[4], bq[2];
#pragma unroll
        for (int i = 0; i < 4; i++) af[i] = ldA(bu, i);
#pragma unroll
        for (int j = 0; j < 2; j++) bq[j] = ldB(bu, j);
        __builtin_amdgcn_s_setprio(1);
#pragma unroll
        for (int i = 0; i < 4; i++)
#pragma unroll
            for (int j = 0; j < 2; j++)
                acc[i][j] = __builtin_amdgcn_mfma_f32_16x16x32_bf16(
                    af[i], bq[j], acc[i][j], 0, 0, 0);
        __builtin_amdgcn_s_setprio(0);
    }
#pragma unroll
    for (int mi = 0; mi < 4; mi++)
#pragma unroll
        for (int r = 0; r < 4; r++) {
            int gr = rowbase + wrbase + mi * 16 + lg * 4 + r;
            if (gr >= rowlim) continue;
            long crow = PC ? (long)perm[gr] : (long)gr;
#pragma unroll
            for (int ni = 0; ni < 2; ni++) {
                long col = n0 + wcbase + ni * 16 + lr;
                long idx = crow * (long)N + col;
                ((float*)Cv)[idx] = resid[idx] + acc[mi][ni][r];
            }
        }
}

// ---------------- q/k fuse: per-head rmsnorm (weight by mask), RoPE -> bf16 [B,H,S,HD]
__global__ __launch_bounds__(256) void qk_fuse(
    const u16* __restrict__ p, const int* __restrict__ mask,
    const float* __restrict__ cs, const float* __restrict__ sn,
    const float* __restrict__ nwt, const float* __restrict__ nwv,
    u16* __restrict__ out, int H, int stride)
{
    int wave = threadIdx.x >> 6, lane = threadIdx.x & 63;
    int gw = blockIdx.x * 4 + wave;
    int tok = gw / H, h = gw % H;
    int b = tok >> 11, s = tok & 2047;
    const u16* src = p + (long)tok * stride + h * 128;
    const float* w = mask[tok] ? nwv : nwt;
    int d = lane * 2;
    float yx = bf2f(src[d]), yy = bf2f(src[d + 1]);
    float ss = yx * yx + yy * yy;
#pragma unroll
    for (int m = 1; m < 64; m <<= 1) ss += __shfl_xor(ss, m);
    float inv = rsqrtf(ss * (1.0f / 128.0f) + 1e-6f);
    float y0 = yx * inv * w[d], y1 = yy * inv * w[d + 1];
    float o0 = __shfl_xor(y0, 32), o1 = __shfl_xor(y1, 32);
    float sgn = (lane < 32) ? -1.0f : 1.0f;
    const float* cp = cs + (long)tok * 128 + d;
    const float* spn = sn + (long)tok * 128 + d;
    float r0 = y0 * cp[0] + sgn * o0 * spn[0];
    float r1 = y1 * cp[1] + sgn * o1 * spn[1];
    u16* op = out + (((long)b * H + h) * 2048 + s) * 128 + d;
    op[0] = f2bf(r0); op[1] = f2bf(r1);
}

// ---------------- v: transpose to [B,NKV,HD,S] bf16
__global__ __launch_bounds__(256) void v_fuse(
    const u16* __restrict__ vsrc, u16* __restrict__ outv, int stride)
{
    __shared__ u16 tile[32][33];
    int s0 = blockIdx.x * 32, d0 = blockIdx.y * 32;
    int bkv = blockIdx.z, b = bkv >> 3, kv = bkv & 7;
    int tx = threadIdx.x, ty = threadIdx.y;
#pragma unroll
    for (int i = 0; i < 32; i += 8) {
        long tok = (long)b * 2048 + s0 + ty + i;
        tile[ty + i][tx] = vsrc[tok * stride + kv * 128 + d0 + tx];
    }
    __syncthreads();
#pragma unroll
    for (int i = 0; i < 32; i += 8)
        outv[(((long)b * 8 + kv) * 128 + d0 + ty + i) * 2048 + s0 + tx] =
            tile[tx][ty + i];
}

// ---------------- flash attention v3: causal GQA, FIXED max bound, KVBLK=64,
// single-buffer static LDS 42KB (~3 blocks/CU), v1's sync-stage-sync schedule
// (halved barrier count vs KVBLK=32). Numerics identical to v1/v2 (validated).
__global__ __launch_bounds__(256) void attn_fwd(
    const u16* __restrict__ q, const u16* __restrict__ k,
    const u16* __restrict__ v, u16* __restrict__ out)
{
    __shared__ u16 Ks[64 * 128];        // 16KB, rows 256B, 8-slot swizzle
    __shared__ u16 Vs[128 * 64];        // 16KB, V^T rows 128B, 8-slot swizzle
    __shared__ u16 Ps[4][16][72];       // 9KB
    const int tid = threadIdx.x, wave = tid >> 6, lane = tid & 63;
    const int lr = lane & 15, lg = lane >> 4;
    const int b = blockIdx.z, h = blockIdx.y, q0 = blockIdx.x * 64;
    const int kvh = h >> 1;
    const u16* qp = q + (((long)b * 16 + h) * 2048 + q0 + wave * 16) * 128;
    bf16x8 qf[4];
#pragma unroll
    for (int f = 0; f < 4; f++)
        qf[f] = *(const bf16x8*)(qp + (long)lr * 128 + f * 32 + lg * 8);
    const char* kbase = (const char*)(k + ((long)b * 8 + kvh) * 2048 * 128);
    const char* vbase = (const char*)(v + ((long)b * 8 + kvh) * 128 * 2048);
    f32x4 o[8] = {};
    float lsum[4] = {};
    const float sc2 = 0.08838834764831845f * 1.44269504088896f;
    const float MB = 16.5f;
    const int ntiles = (q0 >> 6) + 1;
    for (int t = 0; t < ntiles; ++t) {
        long kv0 = (long)t * 64;
        __syncthreads();                 // prior tile's reads complete
#pragma unroll
        for (int c = 0; c < 4; c++) {
            int L = c * 4096 + tid * 16;
            {   // K tile [64][128] bf16
                int row = L >> 8, cb = L & 255;
                glds16(kbase + (kv0 + row) * 256 + (cb ^ ((row & 7) << 4)),
                       (char*)Ks + L);
            }
            {   // V^T tile [128][64] bf16
                int row = L >> 7, cb = L & 127;
                glds16(vbase + (long)row * 4096 + kv0 * 2 + (cb ^ ((row & 7) << 4)),
                       (char*)Vs + L);
            }
        }
        __syncthreads();                 // staged data visible
        // QK^T: 4 n-frags x 4 k-chunks
        f32x4 s[4] = {};
#pragma unroll
        for (int nf = 0; nf < 4; ++nf)
#pragma unroll
            for (int f = 0; f < 4; ++f) {
                int row = nf * 16 + lr;
                int cb = (f * 64 + lg * 16) ^ ((row & 7) << 4);
                bf16x8 kf = *(const bf16x8*)((const char*)Ks + row * 256 + cb);
                s[nf] = __builtin_amdgcn_mfma_f32_16x16x32_bf16(qf[f], kf, s[nf], 0, 0, 0);
            }
        // fixed-max softmax + P to LDS
#pragma unroll
        for (int r = 0; r < 4; r++) {
            int rowg = q0 + wave * 16 + lg * 4 + r;
            u16* prow = &Ps[wave][lg * 4 + r][0];
            float ls = 0.0f;
#pragma unroll
            for (int nf = 0; nf < 4; nf++) {
                float sv = s[nf][r] * sc2 - MB;
                if (kv0 + nf * 16 + lr > rowg) sv = -1e30f;
                float p = exp2f(sv);
                ls += p;
                prow[nf * 16 + lr] = f2bf(p);
            }
            lsum[r] += ls;
        }
        // PV
        bf16x8 pf[2];
#pragma unroll
        for (int kk = 0; kk < 2; kk++)
            pf[kk] = *(const bf16x8*)&Ps[wave][lr][kk * 32 + lg * 8];
#pragma unroll
        for (int ni = 0; ni < 8; ni++)
#pragma unroll
            for (int kk = 0; kk < 2; kk++) {
                int row = ni * 16 + lr;
                int cb = (kk * 64 + lg * 16) ^ ((row & 7) << 4);
                bf16x8 vf = *(const bf16x8*)((const char*)Vs + row * 128 + cb);
                o[ni] = __builtin_amdgcn_mfma_f32_16x16x32_bf16(pf[kk], vf, o[ni], 0, 0, 0);
            }
    }
#pragma unroll
    for (int r = 0; r < 4; r++)
#pragma unroll
        for (int mm = 1; mm < 16; mm <<= 1) lsum[r] += __shfl_xor(lsum[r], mm);
#pragma unroll
    for (int ni = 0; ni < 8; ni++)
#pragma unroll
        for (int r = 0; r < 4; r++) {
            long row = (long)b * 2048 + q0 + wave * 16 + lg * 4 + r;
            out[row * 2048 + h * 128 + ni * 16 + lr] = f2bf(o[ni][r] / lsum[r]);
        }
}

extern "C" void kernel_launch(void* const* d_in, const int* in_sizes, int n_in,
                              void* d_out, int out_size, void* d_ws, size_t ws_size,
                              hipStream_t stream)
{
    const float* x    = (const float*)d_in[0];
    const float* cosp = (const float*)d_in[1];
    const float* sinp = (const float*)d_in[2];
    const int*   mask = (const int*)d_in[3];
    const float* anw  = (const float*)d_in[4];
    const float* fnw  = (const float*)d_in[5];
    const float* wq   = (const float*)d_in[6];
    const float* wk   = (const float*)d_in[7];
    const float* wv   = (const float*)d_in[8];
    const float* wo   = (const float*)d_in[9];
    const float* mwq  = (const float*)d_in[10];
    const float* mwk  = (const float*)d_in[11];
    const float* mwv  = (const float*)d_in[12];
    const float* mwo  = (const float*)d_in[13];
    const float* gw   = (const float*)d_in[14];
    const float* uw   = (const float*)d_in[15];
    const float* dw   = (const float*)d_in[16];
    const float* mgw  = (const float*)d_in[17];
    const float* muw  = (const float*)d_in[18];
    const float* mdw  = (const float*)d_in[19];
    const float* qnw  = (const float*)d_in[20];
    const float* knw  = (const float*)d_in[21];
    const float* mqnw = (const float*)d_in[22];
    const float* mknw = (const float*)d_in[23];

    // ---- workspace layout (240 MB + 16KB), explicit overlays
    char* base = (char*)d_ws;
    u16* wA0   = (u16*)(base);                     // 32MB  weights slot A (text)
    u16* wA1   = (u16*)(base + (32u << 20));       // 32MB  weights slot A (vision)
    u16* wB0   = (u16*)(base + (64u << 20));       // 32MB  weights slot B (text, FFN up)
    u16* wB1   = (u16*)(base + (96u << 20));       // 32MB  weights slot B (vision, FFN up)
    u16* hbf   = (u16*)(base + (64u << 20));       // 16MB rms(x) [overlay wB0]
    u16* qkv   = (u16*)(base + (80u << 20));       // 32MB q|k|v proj [4096][4096]
    u16* qb    = (u16*)(base + (112u << 20));      // 16MB roped q
    u16* kb    = (u16*)(base + (128u << 20));      // 8MB
    u16* vb    = (u16*)(base + (136u << 20));      // 8MB
    u16* attnb = (u16*)(base + (144u << 20));      // 16MB (token order)
    u16* e1    = (u16*)(base + (128u << 20));      // 64MB overlay (grouped, FFN phase)
    float* h2  = (float*)(base + (192u << 20));    // 32MB f32 (token order)
    u16* gbf   = (u16*)(base + (224u << 20));      // 16MB
    int* perm  = (int*)(base + (240u << 20));      // 16KB
    int* cnts  = perm + 4096;

    hipFuncSetAttribute((const void*)&gemm32<1, true, true>,
                        hipFuncAttributeMaxDynamicSharedMemorySize, 73728);
    hipFuncSetAttribute((const void*)&gemm_gu,
                        hipFuncAttributeMaxDynamicSharedMemorySize, 49152);

    auto TR = [&](const float* w, u16* dst, int K, int N) {
        transpose_bf16<<<dim3(K / 64, N / 64), 256, 0, stream>>>(w, dst, K, N);
    };

    build_perm<<<1, 1024, 0, stream>>>(mask, perm, cnts);
    rms_x<<<4096, 256, 0, stream>>>(x, anw, hbf);

    // fused q|k|v projection (BK=32 / 72KB, grid 528 ~ 2 blocks/CU)
    TR(wq, wA0, 2048, 2048);
    TR(wk, wA0 + (long)2048 * 2048, 2048, 1024);
    TR(wv, wA0 + (long)3072 * 2048, 2048, 1024);
    TR(mwq, wA1, 2048, 2048);
    TR(mwk, wA1 + (long)2048 * 2048, 2048, 1024);
    TR(mwv, wA1 + (long)3072 * 2048, 2048, 1024);
    gemm32<1, true, true><<<528, 512, 73728, stream>>>(
        hbf, wA0, wA1, (void*)qkv, perm, cnts, 4096, 2048);

    qk_fuse<<<16384, 256, 0, stream>>>(qkv, mask, cosp, sinp, qnw, mqnw, qb, 16, 4096);
    qk_fuse<<<8192, 256, 0, stream>>>(qkv + 2048, mask, cosp, sinp, knw, mknw, kb, 8, 4096);
    v_fuse<<<dim3(64, 4, 16), dim3(32, 8), 0, stream>>>(qkv + 3072, vb, 4096);

    attn_fwd<<<dim3(32, 16, 2), 256, 0, stream>>>(qb, kb, vb, attnb);

    // O-proj fused residual -> h2 = x + attn@woSel (gemmsq 128x128 BK=32, grid 528)
    TR(wo, wA0, 2048, 2048); TR(mwo, wA1, 2048, 2048);
    gemmsq<2, true, true><<<528, 512, 32768, stream>>>(
        attnb, wA0, wA1, (void*)h2, x, perm, cnts, 2048, 2048);

    rms_x<<<4096, 256, 0, stream>>>(h2, fnw, gbf);

    // fused gate+up (drain-dbuf 48KB -> 3 blocks/CU, launch_bounds(512,4)) -> e1;
    // down-proj fused resid -> d_out (r15-proven 128x128 BK=32 / 32KB drain-dbuf)
    TR(gw, wA0, 2048, 8192); TR(mgw, wA1, 2048, 8192);
    TR(uw, wB0, 2048, 8192); TR(muw, wB1, 2048, 8192);
    gemm_gu<<<2112, 512, 49152, stream>>>(
        gbf, wA0, wA1, wB0, wB1, e1, perm, cnts, 8192, 2048);
    TR(dw, wA0, 8192, 2048); TR(mdw, wA1, 8192, 2048);
    gemmsq<2, false, true><<<528, 512, 32768, stream>>>(
        e1, wA0, wA1, (void*)d_out, h2, perm, cnts, 2048, 8192);
}

// Round 20
// 997.053 us; speedup vs baseline: 1.0364x; 1.0364x over previous
//
#include <hip/hip_runtime.h>

typedef unsigned short u16;
typedef __bf16 bf16x8 __attribute__((ext_vector_type(8)));
typedef float f32x4 __attribute__((ext_vector_type(4)));

__device__ __forceinline__ u16 f2bf(float f) {
    unsigned u = __builtin_bit_cast(unsigned, f);
    u += 0x7fffu + ((u >> 16) & 1u);
    return (u16)(u >> 16);
}
__device__ __forceinline__ float bf2f(u16 v) {
    unsigned u = ((unsigned)v) << 16;
    return __builtin_bit_cast(float, u);
}
__device__ __forceinline__ void glds16(const void* g, void* l) {
    __builtin_amdgcn_global_load_lds(
        (const __attribute__((address_space(1))) unsigned*)g,
        (__attribute__((address_space(3))) unsigned*)l, 16, 0, 0);
}

// chunked XCD-local mapping
__device__ __forceinline__ void xcd_map(int bid, int nloc, int TM, int& tm, int& tn)
{
    const int xcd = bid & 7;
    int l = bid >> 3;
    const int per = nloc << 3;
    const int fullC = TM >> 3;
    const int lFull = fullC * per;
    int c, tn_l, tmIn;
    if (l < lFull) { c = l / per; int r = l - c * per; tn_l = r >> 3; tmIn = r & 7; }
    else { int r = l - lFull; int sc = TM - (fullC << 3); c = fullC; tn_l = r / sc; tmIn = r % sc; }
    tm = (c << 3) + tmIn;
    tn = xcd * nloc + tn_l;
}

// pair-swizzle helpers for BK=32 (64B data rows, 128B LDS pairs, 8 phys slots)
__device__ __forceinline__ void swz_src(int r, int sp, int& rs, int& ks)
{
    int e = (((r & 1) << 2) | sp) ^ ((r >> 1) & 7);
    rs = (r & ~1) | (e >> 2);
    ks = e & 3;
}
__device__ __forceinline__ int swz_rd(int row, int lg)
{
    int s8 = (((row & 1) << 2) | lg) ^ ((row >> 1) & 7);
    return (row >> 1) * 128 + s8 * 16;
}

// ---------------- stable partition of tokens by mask: perm = [text..., vision...]
__global__ __launch_bounds__(1024) void build_perm(
    const int* __restrict__ mask, int* __restrict__ perm, int* __restrict__ counts)
{
    __shared__ int sc[1024];
    int t = threadIdx.x;
    int m[4], cnt = 0;
#pragma unroll
    for (int j = 0; j < 4; j++) {
        m[j] = mask[t * 4 + j] != 0;
        cnt += (m[j] == 0);
    }
    sc[t] = cnt;
    __syncthreads();
    for (int off = 1; off < 1024; off <<= 1) {
        int v = (t >= off) ? sc[t - off] : 0;
        __syncthreads();
        sc[t] += v;
        __syncthreads();
    }
    int totT = sc[1023];
    int exT = sc[t] - cnt;
    int exV = t * 4 - exT;
    int pT = exT, pV = totT + exV;
#pragma unroll
    for (int j = 0; j < 4; j++) {
        if (m[j] == 0) perm[pT++] = t * 4 + j;
        else           perm[pV++] = t * 4 + j;
    }
    if (t == 0) { counts[0] = totT; counts[1] = 4096 - totT; }
}

// ---------------- weight transpose + f32->bf16:  W[K][N] f32 -> Wt[N][K] bf16
__global__ __launch_bounds__(256) void transpose_bf16(
    const float* __restrict__ W, u16* __restrict__ Wt, int Kd, int Nd)
{
    __shared__ float tile[64][65];
    int k0 = blockIdx.x * 64, n0 = blockIdx.y * 64;
    int t = threadIdx.x;
    int rr = t >> 4, cc = (t & 15) * 4;
#pragma unroll
    for (int i = 0; i < 4; i++) {
        float4 v = *(const float4*)&W[(long)(k0 + i * 16 + rr) * Nd + n0 + cc];
        tile[i * 16 + rr][cc]     = v.x;
        tile[i * 16 + rr][cc + 1] = v.y;
        tile[i * 16 + rr][cc + 2] = v.z;
        tile[i * 16 + rr][cc + 3] = v.w;
    }
    __syncthreads();
    int nn = t >> 3, k8 = (t & 7) * 8;
#pragma unroll
    for (int i = 0; i < 2; i++) {
        int n = i * 32 + nn;
        u16 pk[8];
#pragma unroll
        for (int j = 0; j < 8; j++) pk[j] = f2bf(tile[k8 + j][n]);
        *(uint4*)&Wt[(long)(n0 + n) * Kd + k0 + k8] = *(const uint4*)pk;
    }
}

// ---------------- rmsnorm (row of 2048, f32 in) -> bf16 out
__global__ __launch_bounds__(256) void rms_x(
    const float* __restrict__ x, const float* __restrict__ w, u16* __restrict__ out)
{
    long row = blockIdx.x;
    int t = threadIdx.x, wave = t >> 6, lane = t & 63;
    const float4* x4 = (const float4*)(x + row * 2048);
    float4 a = x4[2 * t], b = x4[2 * t + 1];
    float ss = a.x*a.x + a.y*a.y + a.z*a.z + a.w*a.w
             + b.x*b.x + b.y*b.y + b.z*b.z + b.w*b.w;
#pragma unroll
    for (int m = 1; m < 64; m <<= 1) ss += __shfl_xor(ss, m);
    __shared__ float red[4];
    if (lane == 0) red[wave] = ss;
    __syncthreads();
    float tot = red[0] + red[1] + red[2] + red[3];
    float inv = rsqrtf(tot * (1.0f / 2048.0f) + 1e-6f);
    const float4* w4 = (const float4*)w;
    float4 wa = w4[2 * t], wb = w4[2 * t + 1];
    u16* op = out + row * 2048 + t * 8;
    op[0] = f2bf(a.x * inv * wa.x); op[1] = f2bf(a.y * inv * wa.y);
    op[2] = f2bf(a.z * inv * wa.z); op[3] = f2bf(a.w * inv * wa.w);
    op[4] = f2bf(b.x * inv * wb.x); op[5] = f2bf(b.y * inv * wb.y);
    op[6] = f2bf(b.z * inv * wb.z); op[7] = f2bf(b.w * inv * wb.w);
}

// ---------------- grouped GEMM, 128x256 tile, BK=32, 8 waves (2Mx4N), wave 64x64.
// Ring-3 LDS = 72KB -> 2 blocks/CU. Counted vmcnt(3), 1 barrier per K-tile.
// Pair-swizzled LDS. EPI 1: C bf16.
template <int EPI, bool PG, bool PC>
__global__ __launch_bounds__(512, 4) void gemm32(
    const u16* __restrict__ A, const u16* __restrict__ Bt0, const u16* __restrict__ Bt1,
    void* __restrict__ Cv,
    const int* __restrict__ perm, const int* __restrict__ counts, int N, int K)
{
    extern __shared__ u16 lds[];   // 3 x (A 8KB + B 16KB) = 72KB
    int tm, tn;
    xcd_map(blockIdx.x, N >> 11, 33, tm, tn);
    const int nT = counts[0];
    const int tT = (nT + 127) >> 7, tV = (4096 - nT + 127) >> 7;
    if (tm >= tT + tV) return;
    const bool vis = tm >= tT;
    const u16* Bt = vis ? Bt1 : Bt0;
    const int rowbase = vis ? nT + (tm - tT) * 128 : tm * 128;
    const int rowlim = vis ? 4096 : nT;
    const int tid = threadIdx.x;
    const int wave = tid >> 6, lane = tid & 63;
    const int wrbase = (wave >> 2) * 64, wcbase = (wave & 3) * 64;
    const int lr = lane & 15, lg = lane >> 4;
    const int n0 = tn * 256;
    const int t4 = tid >> 2, sp = tid & 3;
    const char* aSrc;
    const char* bSrc[2];
    {
        int rs, ks; swz_src(t4, sp, rs, ks);
        int gr = rowbase + rs; gr = gr < 4095 ? gr : 4095;
        long ar = PG ? perm[gr] : gr;
        aSrc = (const char*)A + ar * (long)K * 2 + ks * 16;
    }
#pragma unroll
    for (int c = 0; c < 2; c++) {
        int r = c * 128 + t4;
        int rs, ks; swz_src(r, sp, rs, ks);
        bSrc[c] = (const char*)Bt + (long)(n0 + rs) * K * 2 + ks * 16;
    }
    auto stage = [&](int kt, int bu) {
        char* ab = (char*)lds + bu * 24576;
        long ko = (long)kt * 64;
        glds16(aSrc + ko, ab + tid * 16);
#pragma unroll
        for (int c = 0; c < 2; c++)
            glds16(bSrc[c] + ko, ab + 8192 + c * 8192 + tid * 16);
    };
    auto ldA = [&](int bu, int mi) -> bf16x8 {
        const char* ab = (const char*)lds + bu * 24576;
        int row = wrbase + mi * 16 + lr;
        return *(const bf16x8*)(ab + swz_rd(row, lg));
    };
    auto ldB = [&](int bu, int ni) -> bf16x8 {
        const char* bb = (const char*)lds + bu * 24576 + 8192;
        int row = wcbase + ni * 16 + lr;
        return *(const bf16x8*)(bb + swz_rd(row, lg));
    };

    f32x4 acc[4][4] = {};
    const int nkt = K >> 5;
    stage(0, 0);
    stage(1, 1);
    for (int kt = 0; kt < nkt; ++kt) {
        const int bu = kt % 3;
        if (kt == nkt - 1) asm volatile("s_waitcnt vmcnt(0)" ::: "memory");
        else               asm volatile("s_waitcnt vmcnt(3)" ::: "memory");
        __builtin_amdgcn_s_barrier();
        if (kt + 2 < nkt) stage(kt + 2, (kt + 2) % 3);
        bf16x8 af[4], bq[4];
#pragma unroll
        for (int i = 0; i < 4; i++) af[i] = ldA(bu, i);
#pragma unroll
        for (int j = 0; j < 4; j++) bq[j] = ldB(bu, j);
        __builtin_amdgcn_s_setprio(1);
#pragma unroll
        for (int i = 0; i < 4; i++)
#pragma unroll
            for (int j = 0; j < 4; j++)
                acc[i][j] = __builtin_amdgcn_mfma_f32_16x16x32_bf16(
                    af[i], bq[j], acc[i][j], 0, 0, 0);
        __builtin_amdgcn_s_setprio(0);
    }
#pragma unroll
    for (int mi = 0; mi < 4; mi++)
#pragma unroll
        for (int r = 0; r < 4; r++) {
            int gr = rowbase + wrbase + mi * 16 + lg * 4 + r;
            if (gr >= rowlim) continue;
            long crow = PC ? (long)perm[gr] : (long)gr;
#pragma unroll
            for (int ni = 0; ni < 4; ni++) {
                long col = n0 + wcbase + ni * 16 + lr;
                ((u16*)Cv)[crow * (long)N + col] = f2bf(acc[mi][ni][r]);
            }
        }
}

// ---------------- fused gate+up, 128M x dual-128N, BK=32, ring-3 = 72KB (2 blocks/CU).
// Counted vmcnt(3), launch_bounds(512,4) (r14: (512,6) spills; r19: drain-dbuf@3blk
// slower). Pair-swizzled LDS. e1 = silu(A@Wg)*(A@Wu), grouped rows.
__global__ __launch_bounds__(512, 4) void gemm_gu(
    const u16* __restrict__ A,
    const u16* __restrict__ Bg0, const u16* __restrict__ Bg1,
    const u16* __restrict__ Bu0, const u16* __restrict__ Bu1,
    u16* __restrict__ C,
    const int* __restrict__ perm, const int* __restrict__ counts, int N, int K)
{
    extern __shared__ u16 lds[];   // 3 x (A 8KB + Bg 8KB + Bu 8KB) = 72KB
    int tm, tn;
    xcd_map(blockIdx.x, N >> 10, 33, tm, tn);
    const int nT = counts[0];
    const int tT = (nT + 127) >> 7, tV = (4096 - nT + 127) >> 7;
    if (tm >= tT + tV) return;
    const bool vis = tm >= tT;
    const u16* Bg = vis ? Bg1 : Bg0;
    const u16* Bu = vis ? Bu1 : Bu0;
    const int rowbase = vis ? nT + (tm - tT) * 128 : tm * 128;
    const int rowlim = vis ? 4096 : nT;
    const int tid = threadIdx.x;
    const int wave = tid >> 6, lane = tid & 63;
    const int wrbase = (wave >> 2) * 64, wcbase = (wave & 3) * 32;
    const int lr = lane & 15, lg = lane >> 4;
    const int n0 = tn * 128;
    const int t4 = tid >> 2, sp = tid & 3;
    const char *aSrc, *gSrc, *uSrc;
    {
        int rs, ks; swz_src(t4, sp, rs, ks);
        int gr = rowbase + rs; gr = gr < 4095 ? gr : 4095;
        long ar = (long)perm[gr];
        aSrc = (const char*)A + ar * (long)K * 2 + ks * 16;
        gSrc = (const char*)Bg + (long)(n0 + rs) * K * 2 + ks * 16;
        uSrc = (const char*)Bu + (long)(n0 + rs) * K * 2 + ks * 16;
    }
    auto stage = [&](int kt, int bu) {
        char* ab = (char*)lds + bu * 24576;
        long ko = (long)kt * 64;
        glds16(aSrc + ko, ab + tid * 16);
        glds16(gSrc + ko, ab + 8192 + tid * 16);
        glds16(uSrc + ko, ab + 16384 + tid * 16);
    };
    auto ldA = [&](int bu, int mi) -> bf16x8 {
        const char* ab = (const char*)lds + bu * 24576;
        int row = wrbase + mi * 16 + lr;
        return *(const bf16x8*)(ab + swz_rd(row, lg));
    };
    auto ldGU = [&](int bu, int sub, int ni) -> bf16x8 {
        const char* p = (const char*)lds + bu * 24576 + 8192 + sub * 8192;
        int row = wcbase + ni * 16 + lr;
        return *(const bf16x8*)(p + swz_rd(row, lg));
    };

    f32x4 accg[4][2] = {}, accu[4][2] = {};
    const int nkt = K >> 5;
    stage(0, 0);
    stage(1, 1);
    for (int kt = 0; kt < nkt; ++kt) {
        const int bu = kt % 3;
        if (kt == nkt - 1) asm volatile("s_waitcnt vmcnt(0)" ::: "memory");
        else               asm volatile("s_waitcnt vmcnt(3)" ::: "memory");
        __builtin_amdgcn_s_barrier();
        if (kt + 2 < nkt) stage(kt + 2, (kt + 2) % 3);
        bf16x8 af[4], bg[2], bv[2];
#pragma unroll
        for (int i = 0; i < 4; i++) af[i] = ldA(bu, i);
#pragma unroll
        for (int j = 0; j < 2; j++) {
            bg[j] = ldGU(bu, 0, j);
            bv[j] = ldGU(bu, 1, j);
        }
        __builtin_amdgcn_s_setprio(1);
#pragma unroll
        for (int i = 0; i < 4; i++)
#pragma unroll
            for (int j = 0; j < 2; j++) {
                accg[i][j] = __builtin_amdgcn_mfma_f32_16x16x32_bf16(
                    af[i], bg[j], accg[i][j], 0, 0, 0);
                accu[i][j] = __builtin_amdgcn_mfma_f32_16x16x32_bf16(
                    af[i], bv[j], accu[i][j], 0, 0, 0);
            }
        __builtin_amdgcn_s_setprio(0);
    }
#pragma unroll
    for (int mi = 0; mi < 4; mi++)
#pragma unroll
        for (int r = 0; r < 4; r++) {
            int gr = rowbase + wrbase + mi * 16 + lg * 4 + r;
            if (gr >= rowlim) continue;
#pragma unroll
            for (int ni = 0; ni < 2; ni++) {
                long col = n0 + wcbase + ni * 16 + lr;
                float g = accg[mi][ni][r], u = accu[mi][ni][r];
                C[(long)gr * N + col] = f2bf(g / (1.0f + __expf(-g)) * u);
            }
        }
}

// ---------------- grouped GEMM, 128x128 tile, BK=32, drain double-buffer 32KB,
// pair-swizzled (r15-proven). Used for O-proj AND down-proj.
// EPI 2: C f32 = resid[idx] + acc.
template <int EPI, bool PG, bool PC>
__global__ __launch_bounds__(512, 4) void gemmsq(
    const u16* __restrict__ A, const u16* __restrict__ Bt0, const u16* __restrict__ Bt1,
    void* __restrict__ Cv, const float* __restrict__ resid,
    const int* __restrict__ perm, const int* __restrict__ counts, int N, int K)
{
    extern __shared__ u16 lds[];   // 2 x (A 8KB + B 8KB) = 32KB
    int tm, tn;
    xcd_map(blockIdx.x, N >> 10, 33, tm, tn);
    const int nT = counts[0];
    const int tT = (nT + 127) >> 7, tV = (4096 - nT + 127) >> 7;
    if (tm >= tT + tV) return;
    const bool vis = tm >= tT;
    const u16* Bt = vis ? Bt1 : Bt0;
    const int rowbase = vis ? nT + (tm - tT) * 128 : tm * 128;
    const int rowlim = vis ? 4096 : nT;
    const int tid = threadIdx.x;
    const int wave = tid >> 6, lane = tid & 63;
    const int wrbase = (wave >> 2) * 64, wcbase = (wave & 3) * 32;
    const int lr = lane & 15, lg = lane >> 4;
    const int n0 = tn * 128;
    const int t4 = tid >> 2, sp = tid & 3;
    const char *aSrc, *bSrc;
    {
        int rs, ks; swz_src(t4, sp, rs, ks);
        int gr = rowbase + rs; gr = gr < 4095 ? gr : 4095;
        long ar = PG ? (long)perm[gr] : (long)gr;
        aSrc = (const char*)A + ar * (long)K * 2 + ks * 16;
        bSrc = (const char*)Bt + (long)(n0 + rs) * K * 2 + ks * 16;
    }
    auto stage = [&](int kt, int bu) {
        char* ab = (char*)lds + bu * 16384;
        long ko = (long)kt * 64;
        glds16(aSrc + ko, ab + tid * 16);
        glds16(bSrc + ko, ab + 8192 + tid * 16);
    };
    auto ldA = [&](int bu, int mi) -> bf16x8 {
        const char* ab = (const char*)lds + bu * 16384;
        int row = wrbase + mi * 16 + lr;
        return *(const bf16x8*)(ab + swz_rd(row, lg));
    };
    auto ldB = [&](int bu, int ni) -> bf16x8 {
        const char* bb = (const char*)lds + bu * 16384 + 8192;
        int row = wcbase + ni * 16 + lr;
        return *(const bf16x8*)(bb + swz_rd(row, lg));
    };

    f32x4 acc[4][2] = {};
    const int nkt = K >> 5;
    stage(0, 0);
    for (int kt = 0; kt < nkt; ++kt) {
        const int bu = kt & 1;
        __syncthreads();
        if (kt + 1 < nkt) stage(kt + 1, bu ^ 1);
        bf16x8 af[4], bq[2];
#pragma unroll
        for (int i = 0; i < 4; i++) af[i] = ldA(bu, i);
#pragma unroll
        for (int j = 0; j < 2; j++) bq[j] = ldB(bu, j);
        __builtin_amdgcn_s_setprio(1);
#pragma unroll
        for (int i = 0; i < 4; i++)
#pragma unroll
            for (int j = 0; j < 2; j++)
                acc[i][j] = __builtin_amdgcn_mfma_f32_16x16x32_bf16(
                    af[i], bq[j], acc[i][j], 0, 0, 0);
        __builtin_amdgcn_s_setprio(0);
    }
#pragma unroll
    for (int mi = 0; mi < 4; mi++)
#pragma unroll
        for (int r = 0; r < 4; r++) {
            int gr = rowbase + wrbase + mi * 16 + lg * 4 + r;
            if (gr >= rowlim) continue;
            long crow = PC ? (long)perm[gr] : (long)gr;
#pragma unroll
            for (int ni = 0; ni < 2; ni++) {
                long col = n0 + wcbase + ni * 16 + lr;
                long idx = crow * (long)N + col;
                ((float*)Cv)[idx] = resid[idx] + acc[mi][ni][r];
            }
        }
}

// ---------------- q/k fuse: per-head rmsnorm (weight by mask), RoPE -> bf16 [B,H,S,HD]
__global__ __launch_bounds__(256) void qk_fuse(
    const u16* __restrict__ p, const int* __restrict__ mask,
    const float* __restrict__ cs, const float* __restrict__ sn,
    const float* __restrict__ nwt, const float* __restrict__ nwv,
    u16* __restrict__ out, int H, int stride)
{
    int wave = threadIdx.x >> 6, lane = threadIdx.x & 63;
    int gw = blockIdx.x * 4 + wave;
    int tok = gw / H, h = gw % H;
    int b = tok >> 11, s = tok & 2047;
    const u16* src = p + (long)tok * stride + h * 128;
    const float* w = mask[tok] ? nwv : nwt;
    int d = lane * 2;
    float yx = bf2f(src[d]), yy = bf2f(src[d + 1]);
    float ss = yx * yx + yy * yy;
#pragma unroll
    for (int m = 1; m < 64; m <<= 1) ss += __shfl_xor(ss, m);
    float inv = rsqrtf(ss * (1.0f / 128.0f) + 1e-6f);
    float y0 = yx * inv * w[d], y1 = yy * inv * w[d + 1];
    float o0 = __shfl_xor(y0, 32), o1 = __shfl_xor(y1, 32);
    float sgn = (lane < 32) ? -1.0f : 1.0f;
    const float* cp = cs + (long)tok * 128 + d;
    const float* spn = sn + (long)tok * 128 + d;
    float r0 = y0 * cp[0] + sgn * o0 * spn[0];
    float r1 = y1 * cp[1] + sgn * o1 * spn[1];
    u16* op = out + (((long)b * H + h) * 2048 + s) * 128 + d;
    op[0] = f2bf(r0); op[1] = f2bf(r1);
}

// ---------------- v: transpose to [B,NKV,HD,S] bf16
__global__ __launch_bounds__(256) void v_fuse(
    const u16* __restrict__ vsrc, u16* __restrict__ outv, int stride)
{
    __shared__ u16 tile[32][33];
    int s0 = blockIdx.x * 32, d0 = blockIdx.y * 32;
    int bkv = blockIdx.z, b = bkv >> 3, kv = bkv & 7;
    int tx = threadIdx.x, ty = threadIdx.y;
#pragma unroll
    for (int i = 0; i < 32; i += 8) {
        long tok = (long)b * 2048 + s0 + ty + i;
        tile[ty + i][tx] = vsrc[tok * stride + kv * 128 + d0 + tx];
    }
    __syncthreads();
#pragma unroll
    for (int i = 0; i < 32; i += 8)
        outv[(((long)b * 8 + kv) * 128 + d0 + ty + i) * 2048 + s0 + tx] =
            tile[tx][ty + i];
}

// ---------------- flash attention (r15/r18-proven v1): causal GQA, FIXED max bound,
// KVBLK=32, static 21.5KB LDS (~7 blocks/CU). q[B,16,S,128], k[B,8,S,128], v[B,8,128,S]
__global__ __launch_bounds__(256) void attn_fwd(
    const u16* __restrict__ q, const u16* __restrict__ k,
    const u16* __restrict__ v, u16* __restrict__ out)
{
    __shared__ u16 Ks[32 * 128];
    __shared__ u16 Vs[128 * 32];
    __shared__ u16 Ps[4][16][40];
    const int tid = threadIdx.x, wave = tid >> 6, lane = tid & 63;
    const int lr = lane & 15, lg = lane >> 4;
    const int b = blockIdx.z, h = blockIdx.y, q0 = blockIdx.x * 64;
    const int kvh = h >> 1;
    const u16* qp = q + (((long)b * 16 + h) * 2048 + q0 + wave * 16) * 128;
    bf16x8 qf[4];
#pragma unroll
    for (int f = 0; f < 4; f++)
        qf[f] = *(const bf16x8*)(qp + (long)lr * 128 + f * 32 + lg * 8);
    const char* kbase = (const char*)(k + ((long)b * 8 + kvh) * 2048 * 128);
    const char* vbase = (const char*)(v + ((long)b * 8 + kvh) * 128 * 2048);
    f32x4 o[8] = {};
    float lsum[4] = {};
    const float sc2 = 0.08838834764831845f * 1.44269504088896f;
    const float MB = 16.5f;
    const int ntiles = (q0 + 64) >> 5;
    for (int t = 0; t < ntiles; ++t) {
        int kv0 = t * 32;
        __syncthreads();
#pragma unroll
        for (int j = 0; j < 2; j++) {
            int L = (j * 4 + wave) * 1024 + lane * 16;
            {
                int row = L >> 8, cb = L & 255;
                glds16(kbase + (long)(kv0 + row) * 256 + (cb ^ ((row & 7) << 4)),
                       (char*)Ks + (j * 4 + wave) * 1024);
            }
            {
                int row = L >> 6, cb = L & 63;
                glds16(vbase + (long)row * 4096 + kv0 * 2 + (cb ^ ((row & 3) << 4)),
                       (char*)Vs + (j * 4 + wave) * 1024);
            }
        }
        __syncthreads();
        f32x4 s[2] = {};
#pragma unroll
        for (int sub = 0; sub < 2; ++sub)
#pragma unroll
            for (int f = 0; f < 4; ++f) {
                int row = sub * 16 + lr;
                int cb = (f * 64 + lg * 16) ^ ((row & 7) << 4);
                bf16x8 kf = *(const bf16x8*)((const char*)Ks + row * 256 + cb);
                s[sub] = __builtin_amdgcn_mfma_f32_16x16x32_bf16(qf[f], kf, s[sub], 0, 0, 0);
            }
#pragma unroll
        for (int r = 0; r < 4; r++) {
            int rowg = q0 + wave * 16 + lg * 4 + r;
            float s0 = s[0][r] * sc2 - MB; if (kv0 + lr > rowg)      s0 = -1e30f;
            float s1 = s[1][r] * sc2 - MB; if (kv0 + 16 + lr > rowg) s1 = -1e30f;
            float p0 = exp2f(s0), p1 = exp2f(s1);
            lsum[r] += p0 + p1;
            int prow = lg * 4 + r;
            Ps[wave][prow][lr] = f2bf(p0);
            Ps[wave][prow][16 + lr] = f2bf(p1);
        }
        bf16x8 pf = *(const bf16x8*)&Ps[wave][lr][lg * 8];
#pragma unroll
        for (int ni = 0; ni < 8; ni++) {
            int row = ni * 16 + lr;
            int cb = (lg * 16) ^ ((row & 3) << 4);
            bf16x8 vf = *(const bf16x8*)((const char*)Vs + row * 64 + cb);
            o[ni] = __builtin_amdgcn_mfma_f32_16x16x32_bf16(pf, vf, o[ni], 0, 0, 0);
        }
    }
#pragma unroll
    for (int r = 0; r < 4; r++)
#pragma unroll
        for (int mm = 1; mm < 16; mm <<= 1) lsum[r] += __shfl_xor(lsum[r], mm);
#pragma unroll
    for (int ni = 0; ni < 8; ni++)
#pragma unroll
        for (int r = 0; r < 4; r++) {
            long row = (long)b * 2048 + q0 + wave * 16 + lg * 4 + r;
            out[row * 2048 + h * 128 + ni * 16 + lr] = f2bf(o[ni][r] / lsum[r]);
        }
}

extern "C" void kernel_launch(void* const* d_in, const int* in_sizes, int n_in,
                              void* d_out, int out_size, void* d_ws, size_t ws_size,
                              hipStream_t stream)
{
    const float* x    = (const float*)d_in[0];
    const float* cosp = (const float*)d_in[1];
    const float* sinp = (const float*)d_in[2];
    const int*   mask = (const int*)d_in[3];
    const float* anw  = (const float*)d_in[4];
    const float* fnw  = (const float*)d_in[5];
    const float* wq   = (const float*)d_in[6];
    const float* wk   = (const float*)d_in[7];
    const float* wv   = (const float*)d_in[8];
    const float* wo   = (const float*)d_in[9];
    const float* mwq  = (const float*)d_in[10];
    const float* mwk  = (const float*)d_in[11];
    const float* mwv  = (const float*)d_in[12];
    const float* mwo  = (const float*)d_in[13];
    const float* gw   = (const float*)d_in[14];
    const float* uw   = (const float*)d_in[15];
    const float* dw   = (const float*)d_in[16];
    const float* mgw  = (const float*)d_in[17];
    const float* muw  = (const float*)d_in[18];
    const float* mdw  = (const float*)d_in[19];
    const float* qnw  = (const float*)d_in[20];
    const float* knw  = (const float*)d_in[21];
    const float* mqnw = (const float*)d_in[22];
    const float* mknw = (const float*)d_in[23];

    // ---- workspace layout (240 MB + 16KB), explicit overlays
    char* base = (char*)d_ws;
    u16* wA0   = (u16*)(base);                     // 32MB  weights slot A (text)
    u16* wA1   = (u16*)(base + (32u << 20));       // 32MB  weights slot A (vision)
    u16* wB0   = (u16*)(base + (64u << 20));       // 32MB  weights slot B (text, FFN up)
    u16* wB1   = (u16*)(base + (96u << 20));       // 32MB  weights slot B (vision, FFN up)
    u16* hbf   = (u16*)(base + (64u << 20));       // 16MB rms(x) [overlay wB0]
    u16* qkv   = (u16*)(base + (80u << 20));       // 32MB q|k|v proj [4096][4096]
    u16* qb    = (u16*)(base + (112u << 20));      // 16MB roped q
    u16* kb    = (u16*)(base + (128u << 20));      // 8MB
    u16* vb    = (u16*)(base + (136u << 20));      // 8MB
    u16* attnb = (u16*)(base + (144u << 20));      // 16MB (token order)
    u16* e1    = (u16*)(base + (128u << 20));      // 64MB overlay (grouped, FFN phase)
    float* h2  = (float*)(base + (192u << 20));    // 32MB f32 (token order)
    u16* gbf   = (u16*)(base + (224u << 20));      // 16MB
    int* perm  = (int*)(base + (240u << 20));      // 16KB
    int* cnts  = perm + 4096;

    hipFuncSetAttribute((const void*)&gemm32<1, true, true>,
                        hipFuncAttributeMaxDynamicSharedMemorySize, 73728);
    hipFuncSetAttribute((const void*)&gemm_gu,
                        hipFuncAttributeMaxDynamicSharedMemorySize, 73728);

    auto TR = [&](const float* w, u16* dst, int K, int N) {
        transpose_bf16<<<dim3(K / 64, N / 64), 256, 0, stream>>>(w, dst, K, N);
    };

    build_perm<<<1, 1024, 0, stream>>>(mask, perm, cnts);
    rms_x<<<4096, 256, 0, stream>>>(x, anw, hbf);

    // fused q|k|v projection (BK=32 / 72KB, grid 528 ~ 2 blocks/CU)
    TR(wq, wA0, 2048, 2048);
    TR(wk, wA0 + (long)2048 * 2048, 2048, 1024);
    TR(wv, wA0 + (long)3072 * 2048, 2048, 1024);
    TR(mwq, wA1, 2048, 2048);
    TR(mwk, wA1 + (long)2048 * 2048, 2048, 1024);
    TR(mwv, wA1 + (long)3072 * 2048, 2048, 1024);
    gemm32<1, true, true><<<528, 512, 73728, stream>>>(
        hbf, wA0, wA1, (void*)qkv, perm, cnts, 4096, 2048);

    qk_fuse<<<16384, 256, 0, stream>>>(qkv, mask, cosp, sinp, qnw, mqnw, qb, 16, 4096);
    qk_fuse<<<8192, 256, 0, stream>>>(qkv + 2048, mask, cosp, sinp, knw, mknw, kb, 8, 4096);
    v_fuse<<<dim3(64, 4, 16), dim3(32, 8), 0, stream>>>(qkv + 3072, vb, 4096);

    attn_fwd<<<dim3(32, 16, 2), 256, 0, stream>>>(qb, kb, vb, attnb);

    // O-proj fused residual -> h2 = x + attn@woSel (gemmsq 128x128 BK=32, grid 528)
    TR(wo, wA0, 2048, 2048); TR(mwo, wA1, 2048, 2048);
    gemmsq<2, true, true><<<528, 512, 32768, stream>>>(
        attnb, wA0, wA1, (void*)h2, x, perm, cnts, 2048, 2048);

    rms_x<<<4096, 256, 0, stream>>>(h2, fnw, gbf);

    // fused gate+up (ring-3 72KB counted vmcnt(3), grid 2112) -> e1 = silu(g)*u;
    // down-proj fused resid -> d_out (r15-proven 128x128 BK=32 / 32KB drain-dbuf)
    TR(gw, wA0, 2048, 8192); TR(mgw, wA1, 2048, 8192);
    TR(uw, wB0, 2048, 8192); TR(muw, wB1, 2048, 8192);
    gemm_gu<<<2112, 512, 73728, stream>>>(
        gbf, wA0, wA1, wB0, wB1, e1, perm, cnts, 8192, 2048);
    TR(dw, wA0, 8192, 2048); TR(mdw, wA1, 8192, 2048);
    gemmsq<2, false, true><<<528, 512, 32768, stream>>>(
        e1, wA0, wA1, (void*)d_out, h2, perm, cnts, 2048, 8192);
}